// Round 2
// baseline (11948.386 us; speedup 1.0000x reference)
//
#include <hip/hip_runtime.h>

// ---------------- problem constants ----------------
#define N_NODES 20000
#define N_EDGES 640000
#define ET 32          // edges per block tile (8 threads per edge row)
#define NT 32          // nodes per block tile
#define RS 132         // LDS row stride in floats (128 used, +4 pad)

// workspace: ONLY accumulators (<= 10.48 MB, proven-safe size)
#define OFF_MACC   0               // [20000*128] f32 accumulator for m_i
#define OFF_SHIFT  2560000         // [20000*3]   f32 accumulator for shifts
#define WS_FLOATS  2620000

#define INV_SQRT_AVG 0.0070714082f   // 1/sqrt(19999)
#define INV_AVG      5.000250e-5f    // 1/19999

__device__ __forceinline__ float silu(float v) {
  return v / (1.0f + __expf(-v));
}

// acc[16] += Xrow(LDS f32, K=128) dot W[k][j0+i]  (W row length 128, f32 global)
__device__ __forceinline__ void gemv_acc(const float* __restrict__ Xrow,
                                         const float* __restrict__ W,
                                         int j0, float acc[16]) {
#pragma unroll 2
  for (int k = 0; k < 128; ++k) {
    float xk = Xrow[k];
    const float4* wr = (const float4*)(W + ((size_t)k << 7) + j0);
#pragma unroll
    for (int i = 0; i < 4; ++i) {
      float4 w = wr[i];
      acc[4 * i + 0] = fmaf(xk, w.x, acc[4 * i + 0]);
      acc[4 * i + 1] = fmaf(xk, w.y, acc[4 * i + 1]);
      acc[4 * i + 2] = fmaf(xk, w.z, acc[4 * i + 2]);
      acc[4 * i + 3] = fmaf(xk, w.w, acc[4 * i + 3]);
    }
  }
}

__device__ __forceinline__ void load_bias(const float* __restrict__ b, int j0,
                                          float acc[16]) {
  const float4* br = (const float4*)(b + j0);
#pragma unroll
  for (int i = 0; i < 4; ++i) {
    float4 v = br[i];
    acc[4 * i + 0] = v.x; acc[4 * i + 1] = v.y;
    acc[4 * i + 2] = v.z; acc[4 * i + 3] = v.w;
  }
}

__device__ __forceinline__ void silu_store(float* __restrict__ Yrow, int j0,
                                           const float acc[16]) {
#pragma unroll
  for (int i = 0; i < 16; ++i) Yrow[j0 + i] = silu(acc[i]);
}

__device__ __forceinline__ void copy_row(float* __restrict__ dstrow,
                                         const float* __restrict__ srcrow, int p) {
  const float4* s4 = (const float4*)srcrow;
  float4* d4 = (float4*)dstrow;
#pragma unroll
  for (int c = 0; c < 4; ++c) d4[p + 8 * c] = s4[p + 8 * c];
}

// ---------------- edge kernel ----------------
__global__ __launch_bounds__(256) void edge_kernel(
    const float* __restrict__ pos, const float* __restrict__ feat,
    const int* __restrict__ snd, const int* __restrict__ rcv,
    const float* __restrict__ pe_w0, const float* __restrict__ pe_b0,
    const float* __restrict__ pe_w1, const float* __restrict__ pe_b1,
    const float* __restrict__ px_w0, const float* __restrict__ px_b0,
    const float* __restrict__ px_w1, const float* __restrict__ px_b1,
    const float* __restrict__ px_out_w, const float* __restrict__ px_out_b,
    const float* __restrict__ e_w, const float* __restrict__ e_b,
    float* __restrict__ m_acc, float* __restrict__ shifts_acc) {
  __shared__ float A[ET * RS];
  __shared__ float Hb[ET * RS];
  __shared__ float Mb[ET * RS];
  __shared__ float lenf[ET];
  __shared__ float vecf[ET][3];
  __shared__ int erl[ET];

  const int tid = threadIdx.x;
  const int e0 = blockIdx.x * ET;
  const int e = tid >> 3;    // 0..31
  const int p = tid & 7;     // 0..7
  const int j0 = p * 16;

  if (tid < ET) {
    int s = snd[e0 + tid], r = rcv[e0 + tid];
    erl[tid] = r;
    float vx = pos[r * 3 + 0] - pos[s * 3 + 0];
    float vy = pos[r * 3 + 1] - pos[s * 3 + 1];
    float vz = pos[r * 3 + 2] - pos[s * 3 + 2];
    float n2 = vx * vx + vy * vy + vz * vz;
    float L = (n2 > 0.0f) ? sqrtf(n2) : 0.0f;
    vecf[tid][0] = vx; vecf[tid][1] = vy; vecf[tid][2] = vz;
    lenf[tid] = L;
  }

  // stage sender feature row
  {
    int sidx = snd[e0 + e];
    copy_row(A + e * RS, feat + (size_t)sidx * 128, p);
  }
  __syncthreads();

  float acc[16];
  // ---- phi_e layer 0 (K=257: sender 128 | receiver 128 | length 1) ----
  load_bias(pe_b0, j0, acc);
  gemv_acc(A + e * RS, pe_w0, j0, acc);
  __syncthreads();  // everyone done reading sender rows

  {
    int ridx = erl[e];
    copy_row(A + e * RS, feat + (size_t)ridx * 128, p);
  }
  __syncthreads();
  gemv_acc(A + e * RS, pe_w0 + 128 * 128, j0, acc);
  {
    float L = lenf[e];
    const float4* wr = (const float4*)(pe_w0 + 256 * 128 + j0);
#pragma unroll
    for (int i = 0; i < 4; ++i) {
      float4 w = wr[i];
      acc[4 * i + 0] = fmaf(L, w.x, acc[4 * i + 0]);
      acc[4 * i + 1] = fmaf(L, w.y, acc[4 * i + 1]);
      acc[4 * i + 2] = fmaf(L, w.z, acc[4 * i + 2]);
      acc[4 * i + 3] = fmaf(L, w.w, acc[4 * i + 3]);
    }
  }
  silu_store(Hb + e * RS, j0, acc);
  __syncthreads();

  // ---- phi_e layer 1: Hb -> Mb (m_ij) ----
  load_bias(pe_b1, j0, acc);
  gemv_acc(Hb + e * RS, pe_w1, j0, acc);
  silu_store(Mb + e * RS, j0, acc);
  __syncthreads();

  // ---- phi_x layer 0: Mb -> A ----
  load_bias(px_b0, j0, acc);
  gemv_acc(Mb + e * RS, px_w0, j0, acc);
  silu_store(A + e * RS, j0, acc);
  __syncthreads();

  // ---- phi_x layer 1: A -> Hb ----
  load_bias(px_b1, j0, acc);
  gemv_acc(A + e * RS, px_w1, j0, acc);
  silu_store(Hb + e * RS, j0, acc);
  __syncthreads();

  // ---- tails: phi_x_out (from Hb=px) and gate e (from Mb=m_ij) ----
  float s1 = 0.0f, s2 = 0.0f;
#pragma unroll
  for (int i = 0; i < 16; ++i) {
    s1 += Hb[e * RS + j0 + i] * px_out_w[j0 + i];
    s2 += Mb[e * RS + j0 + i] * e_w[j0 + i];
  }
  s1 += __shfl_xor(s1, 1); s1 += __shfl_xor(s1, 2); s1 += __shfl_xor(s1, 4);
  s2 += __shfl_xor(s2, 1); s2 += __shfl_xor(s2, 2); s2 += __shfl_xor(s2, 4);
  float phi_x = s1 + px_out_b[0];
  float eg = 1.0f / (1.0f + __expf(-(s2 + e_b[0])));

  int r = erl[e];
#pragma unroll
  for (int i = 0; i < 16; ++i) {
    float m = Mb[e * RS + j0 + i];
    atomicAdd(&m_acc[(size_t)r * 128 + j0 + i], m * eg);
  }
  if (p < 3) {
    float sh = phi_x * vecf[e][p] / (1.0f + lenf[e]);
    atomicAdd(&shifts_acc[(size_t)r * 3 + p], sh);
  }
}

// ---------------- node kernel ----------------
__global__ __launch_bounds__(256) void node_kernel(
    const float* __restrict__ pos, const float* __restrict__ feat,
    const float* __restrict__ ph_w0, const float* __restrict__ ph_b0,
    const float* __restrict__ ph_w1, const float* __restrict__ ph_b1,
    const float* __restrict__ ph_w2, const float* __restrict__ ph_b2,
    const float* __restrict__ m_acc, const float* __restrict__ shifts_acc,
    float* __restrict__ out) {
  __shared__ float A[NT * RS];   // m_i, then h1
  __shared__ float Cb[NT * RS];  // feat (kept for residual)
  __shared__ float Hb[NT * RS];  // h0

  const int tid = threadIdx.x;
  const int n0 = blockIdx.x * NT;
  const int e = tid >> 3;
  const int p = tid & 7;
  const int j0 = p * 16;
  const int n = n0 + e;
  const bool valid = (n < N_NODES);
  const int nc = valid ? n : 0;

  // stage m_i (scaled) and feat
  {
    const float4* mr = (const float4*)(m_acc + (size_t)nc * 128 + j0);
    float* Arow = A + e * RS + j0;
#pragma unroll
    for (int i4 = 0; i4 < 4; ++i4) {
      float4 v = mr[i4];
      Arow[4 * i4 + 0] = v.x * INV_SQRT_AVG;
      Arow[4 * i4 + 1] = v.y * INV_SQRT_AVG;
      Arow[4 * i4 + 2] = v.z * INV_SQRT_AVG;
      Arow[4 * i4 + 3] = v.w * INV_SQRT_AVG;
    }
    copy_row(Cb + e * RS, feat + (size_t)nc * 128, p);
  }
  __syncthreads();

  float acc[16];
  // ---- ph layer 0 (K=256: m_i rows 0..127, feat rows 128..255) ----
  load_bias(ph_b0, j0, acc);
  gemv_acc(A + e * RS, ph_w0, j0, acc);
  gemv_acc(Cb + e * RS, ph_w0 + 128 * 128, j0, acc);
  silu_store(Hb + e * RS, j0, acc);
  __syncthreads();

  // ---- ph layer 1: Hb -> A ----
  load_bias(ph_b1, j0, acc);
  gemv_acc(Hb + e * RS, ph_w1, j0, acc);
  silu_store(A + e * RS, j0, acc);
  __syncthreads();

  // ---- ph layer 2 (no act) + residual ----
  load_bias(ph_b2, j0, acc);
  gemv_acc(A + e * RS, ph_w2, j0, acc);
  if (valid) {
    float* of = out + 60000 + (size_t)n * 128 + j0;
#pragma unroll
    for (int i = 0; i < 16; ++i) of[i] = acc[i] + Cb[e * RS + j0 + i];
  }

  // ---- vectors_out ----
  if (tid < NT * 3) {
    int nl = tid / 3, c = tid - nl * 3;
    int nn = n0 + nl;
    if (nn < N_NODES) {
      out[nn * 3 + c] = pos[nn * 3 + c] + shifts_acc[(size_t)nn * 3 + c] * INV_AVG;
    }
  }
}

// ---------------- launch ----------------
extern "C" void kernel_launch(void* const* d_in, const int* in_sizes, int n_in,
                              void* d_out, int out_size, void* d_ws, size_t ws_size,
                              hipStream_t stream) {
  const float* pos  = (const float*)d_in[0];
  const float* feat = (const float*)d_in[1];
  const float* pe_w0 = (const float*)d_in[2];
  const float* pe_b0 = (const float*)d_in[3];
  const float* pe_w1 = (const float*)d_in[4];
  const float* pe_b1 = (const float*)d_in[5];
  const float* px_w0 = (const float*)d_in[6];
  const float* px_b0 = (const float*)d_in[7];
  const float* px_w1 = (const float*)d_in[8];
  const float* px_b1 = (const float*)d_in[9];
  const float* px_out_w = (const float*)d_in[10];
  const float* px_out_b = (const float*)d_in[11];
  const float* e_w = (const float*)d_in[12];
  const float* e_b = (const float*)d_in[13];
  const float* ph_w0 = (const float*)d_in[14];
  const float* ph_b0 = (const float*)d_in[15];
  const float* ph_w1 = (const float*)d_in[16];
  const float* ph_b1 = (const float*)d_in[17];
  const float* ph_w2 = (const float*)d_in[18];
  const float* ph_b2 = (const float*)d_in[19];
  const int* snd = (const int*)d_in[20];
  const int* rcv = (const int*)d_in[21];
  float* ws = (float*)d_ws;
  float* out = (float*)d_out;

  // zero accumulators (m_acc + shifts_acc) — exactly 10.48 MB
  hipMemsetAsync(d_ws, 0, (size_t)WS_FLOATS * sizeof(float), stream);

  edge_kernel<<<N_EDGES / ET, 256, 0, stream>>>(
      pos, feat, snd, rcv,
      pe_w0, pe_b0, pe_w1, pe_b1,
      px_w0, px_b0, px_w1, px_b1,
      px_out_w, px_out_b, e_w, e_b,
      ws + OFF_MACC, ws + OFF_SHIFT);

  node_kernel<<<(N_NODES + NT - 1) / NT, 256, 0, stream>>>(
      pos, feat, ph_w0, ph_b0, ph_w1, ph_b1, ph_w2, ph_b2,
      ws + OFF_MACC, ws + OFF_SHIFT, out);
}

// Round 3
// 11883.172 us; speedup vs baseline: 1.0055x; 1.0055x over previous
//
#include <hip/hip_runtime.h>

// ---------------- problem constants ----------------
#define N_NODES 20000
#define N_EDGES 640000
#define ET 32          // edges per block (8 threads per edge row)
#define NT 32          // nodes per block
#define RS 132         // node-kernel LDS row stride in floats (+4 pad)

// workspace: ONLY accumulators (<= 10.48 MB, proven-safe size)
#define OFF_MACC   0               // [20000*128] f32 accumulator for m_i
#define OFF_SHIFT  2560000         // [20000*3]   f32 accumulator for shifts
#define WS_FLOATS  2620000

#define INV_SQRT_AVG 0.0070714082f   // 1/sqrt(19999)
#define INV_AVG      5.000250e-5f    // 1/19999

__device__ __forceinline__ float silu(float v) {
  return v / (1.0f + __expf(-v));
}

// ---- depth-4 software-pipelined gemv ----
// acc[16] += X[k ^ sw] * W[k][j0..j0+15], k = 0..127.
// X is an LDS row base; sw is a float-index XOR swizzle (0 for padded layouts).
__device__ __forceinline__ void gemv_pipe(const float* __restrict__ X, int sw,
                                          const float* __restrict__ W, int j0,
                                          float acc[16]) {
  const float4* Wp = (const float4*)(W + j0);   // row stride = 32 float4
  float4 w[4][4];
#pragma unroll
  for (int j = 0; j < 4; ++j)
#pragma unroll
    for (int i = 0; i < 4; ++i) w[j][i] = Wp[j * 32 + i];

  for (int kb = 0; kb < 124; kb += 4) {
#pragma unroll
    for (int j = 0; j < 4; ++j) {
      float xk = X[(kb + j) ^ sw];
#pragma unroll
      for (int i = 0; i < 4; ++i) {
        float4 ww = w[j][i];
        acc[4 * i + 0] = fmaf(xk, ww.x, acc[4 * i + 0]);
        acc[4 * i + 1] = fmaf(xk, ww.y, acc[4 * i + 1]);
        acc[4 * i + 2] = fmaf(xk, ww.z, acc[4 * i + 2]);
        acc[4 * i + 3] = fmaf(xk, ww.w, acc[4 * i + 3]);
      }
#pragma unroll
      for (int i = 0; i < 4; ++i) w[j][i] = Wp[(kb + 4 + j) * 32 + i];
    }
  }
  // epilogue: rows 124..127 already resident in w
#pragma unroll
  for (int j = 0; j < 4; ++j) {
    float xk = X[(124 + j) ^ sw];
#pragma unroll
    for (int i = 0; i < 4; ++i) {
      float4 ww = w[j][i];
      acc[4 * i + 0] = fmaf(xk, ww.x, acc[4 * i + 0]);
      acc[4 * i + 1] = fmaf(xk, ww.y, acc[4 * i + 1]);
      acc[4 * i + 2] = fmaf(xk, ww.z, acc[4 * i + 2]);
      acc[4 * i + 3] = fmaf(xk, ww.w, acc[4 * i + 3]);
    }
  }
}

__device__ __forceinline__ void load_bias(const float* __restrict__ b, int j0,
                                          float acc[16]) {
  const float4* br = (const float4*)(b + j0);
#pragma unroll
  for (int i = 0; i < 4; ++i) {
    float4 v = br[i];
    acc[4 * i + 0] = v.x; acc[4 * i + 1] = v.y;
    acc[4 * i + 2] = v.z; acc[4 * i + 3] = v.w;
  }
}

// store 16 outputs (cols j0..j0+15) of edge-row e into swizzled buffer
template <bool ACT>
__device__ __forceinline__ void store_row_sw(float* __restrict__ buf, int e,
                                             int sw4, int p, const float acc[16]) {
  float4* b4 = (float4*)buf + e * 32;
#pragma unroll
  for (int c = 0; c < 4; ++c) {
    float4 v;
    v.x = ACT ? silu(acc[4 * c + 0]) : acc[4 * c + 0];
    v.y = ACT ? silu(acc[4 * c + 1]) : acc[4 * c + 1];
    v.z = ACT ? silu(acc[4 * c + 2]) : acc[4 * c + 2];
    v.w = ACT ? silu(acc[4 * c + 3]) : acc[4 * c + 3];
    b4[(p * 4 + c) ^ sw4] = v;
  }
}

// stage a 128-float global row into swizzled LDS row e (8 threads, index p)
__device__ __forceinline__ void stage_row_sw(float* __restrict__ buf, int e,
                                             int sw4, int p,
                                             const float* __restrict__ src) {
  const float4* s4 = (const float4*)src;
  float4* d4 = (float4*)buf + e * 32;
#pragma unroll
  for (int c = 0; c < 4; ++c) d4[(p + 8 * c) ^ sw4] = s4[p + 8 * c];
}

__device__ __forceinline__ void silu_store_pad(float* __restrict__ Yrow, int j0,
                                               const float acc[16]) {
#pragma unroll
  for (int i = 0; i < 16; ++i) Yrow[j0 + i] = silu(acc[i]);
}

__device__ __forceinline__ void copy_row_pad(float* __restrict__ dstrow,
                                             const float* __restrict__ srcrow, int p) {
  const float4* s4 = (const float4*)srcrow;
  float4* d4 = (float4*)dstrow;
#pragma unroll
  for (int c = 0; c < 4; ++c) d4[p + 8 * c] = s4[p + 8 * c];
}

// ---------------- edge kernel ----------------
__global__ __launch_bounds__(256, 3) void edge_kernel(
    const float* __restrict__ pos, const float* __restrict__ feat,
    const int* __restrict__ snd, const int* __restrict__ rcv,
    const float* __restrict__ pe_w0, const float* __restrict__ pe_b0,
    const float* __restrict__ pe_w1, const float* __restrict__ pe_b1,
    const float* __restrict__ px_w0, const float* __restrict__ px_b0,
    const float* __restrict__ px_w1, const float* __restrict__ px_b1,
    const float* __restrict__ px_out_w, const float* __restrict__ px_out_b,
    const float* __restrict__ e_w, const float* __restrict__ e_b,
    float* __restrict__ m_acc, float* __restrict__ shifts_acc) {
  __shared__ float A[ET * 128];
  __shared__ float B[ET * 128];
  __shared__ float lenf[ET];
  __shared__ float vecf[ET][3];
  __shared__ int erl[ET];

  const int tid = threadIdx.x;
  const int e0 = blockIdx.x * ET;
  const int e = tid >> 3;           // 0..31
  const int p = tid & 7;            // 0..7
  const int j0 = p * 16;
  const int sw4 = e & 7;            // float4-index XOR mask
  const int sw = sw4 << 2;          // float-index XOR mask

  if (tid < ET) {
    int s = snd[e0 + tid], r = rcv[e0 + tid];
    erl[tid] = r;
    float vx = pos[r * 3 + 0] - pos[s * 3 + 0];
    float vy = pos[r * 3 + 1] - pos[s * 3 + 1];
    float vz = pos[r * 3 + 2] - pos[s * 3 + 2];
    float n2 = vx * vx + vy * vy + vz * vz;
    float L = (n2 > 0.0f) ? sqrtf(n2) : 0.0f;
    vecf[tid][0] = vx; vecf[tid][1] = vy; vecf[tid][2] = vz;
    lenf[tid] = L;
  }

  // stage sender feature row -> A
  stage_row_sw(A, e, sw4, p, feat + (size_t)snd[e0 + e] * 128);
  __syncthreads();

  float acc[16];
  // ---- phi_e layer 0 (K=257: sender 128 | receiver 128 | length 1) ----
  load_bias(pe_b0, j0, acc);
  gemv_pipe(A + e * 128, sw, pe_w0, j0, acc);
  __syncthreads();  // done reading sender rows

  stage_row_sw(A, e, sw4, p, feat + (size_t)erl[e] * 128);
  __syncthreads();
  gemv_pipe(A + e * 128, sw, pe_w0 + 128 * 128, j0, acc);
  {
    float L = lenf[e];
    const float4* wr = (const float4*)(pe_w0 + 256 * 128 + j0);
#pragma unroll
    for (int i = 0; i < 4; ++i) {
      float4 w = wr[i];
      acc[4 * i + 0] = fmaf(L, w.x, acc[4 * i + 0]);
      acc[4 * i + 1] = fmaf(L, w.y, acc[4 * i + 1]);
      acc[4 * i + 2] = fmaf(L, w.z, acc[4 * i + 2]);
      acc[4 * i + 3] = fmaf(L, w.w, acc[4 * i + 3]);
    }
  }
  store_row_sw<true>(B, e, sw4, p, acc);   // h0 = silu(...)
  __syncthreads();

  // ---- phi_e layer 1: B -> m_ij (registers) ----
  load_bias(pe_b1, j0, acc);
  gemv_pipe(B + e * 128, sw, pe_w1, j0, acc);
#pragma unroll
  for (int i = 0; i < 16; ++i) acc[i] = silu(acc[i]);   // m_ij

  // gate e = sigmoid(m_ij . e_w + e_b), reduced over the 8-lane p-octet
  float s2 = 0.0f;
#pragma unroll
  for (int i = 0; i < 16; ++i) s2 += acc[i] * e_w[j0 + i];
  s2 += __shfl_xor(s2, 1); s2 += __shfl_xor(s2, 2); s2 += __shfl_xor(s2, 4);
  float eg = 1.0f / (1.0f + __expf(-(s2 + e_b[0])));

  const int r = erl[e];
#pragma unroll
  for (int i = 0; i < 16; ++i)
    atomicAdd(&m_acc[(size_t)r * 128 + j0 + i], acc[i] * eg);

  // m_ij -> A for phi_x input
  store_row_sw<false>(A, e, sw4, p, acc);
  __syncthreads();

  // ---- phi_x layer 0: A -> B ----
  load_bias(px_b0, j0, acc);
  gemv_pipe(A + e * 128, sw, px_w0, j0, acc);
  store_row_sw<true>(B, e, sw4, p, acc);
  __syncthreads();

  // ---- phi_x layer 1: B -> px (registers), then Dense(1) tail ----
  load_bias(px_b1, j0, acc);
  gemv_pipe(B + e * 128, sw, px_w1, j0, acc);
  float s1 = 0.0f;
#pragma unroll
  for (int i = 0; i < 16; ++i) s1 += silu(acc[i]) * px_out_w[j0 + i];
  s1 += __shfl_xor(s1, 1); s1 += __shfl_xor(s1, 2); s1 += __shfl_xor(s1, 4);
  float phi_x = s1 + px_out_b[0];

  if (p < 3) {
    float sh = phi_x * vecf[e][p] / (1.0f + lenf[e]);
    atomicAdd(&shifts_acc[(size_t)r * 3 + p], sh);
  }
}

// ---------------- node kernel ----------------
__global__ __launch_bounds__(256) void node_kernel(
    const float* __restrict__ pos, const float* __restrict__ feat,
    const float* __restrict__ ph_w0, const float* __restrict__ ph_b0,
    const float* __restrict__ ph_w1, const float* __restrict__ ph_b1,
    const float* __restrict__ ph_w2, const float* __restrict__ ph_b2,
    const float* __restrict__ m_acc, const float* __restrict__ shifts_acc,
    float* __restrict__ out) {
  __shared__ float A[NT * RS];   // m_i, then h1
  __shared__ float Cb[NT * RS];  // feat (kept for residual)
  __shared__ float Hb[NT * RS];  // h0

  const int tid = threadIdx.x;
  const int n0 = blockIdx.x * NT;
  const int e = tid >> 3;
  const int p = tid & 7;
  const int j0 = p * 16;
  const int n = n0 + e;
  const bool valid = (n < N_NODES);
  const int nc = valid ? n : 0;

  {
    const float4* mr = (const float4*)(m_acc + (size_t)nc * 128 + j0);
    float* Arow = A + e * RS + j0;
#pragma unroll
    for (int i4 = 0; i4 < 4; ++i4) {
      float4 v = mr[i4];
      Arow[4 * i4 + 0] = v.x * INV_SQRT_AVG;
      Arow[4 * i4 + 1] = v.y * INV_SQRT_AVG;
      Arow[4 * i4 + 2] = v.z * INV_SQRT_AVG;
      Arow[4 * i4 + 3] = v.w * INV_SQRT_AVG;
    }
    copy_row_pad(Cb + e * RS, feat + (size_t)nc * 128, p);
  }
  __syncthreads();

  float acc[16];
  // ---- ph layer 0 (K=256: m_i rows, then feat rows) ----
  load_bias(ph_b0, j0, acc);
  gemv_pipe(A + e * RS, 0, ph_w0, j0, acc);
  gemv_pipe(Cb + e * RS, 0, ph_w0 + 128 * 128, j0, acc);
  silu_store_pad(Hb + e * RS, j0, acc);
  __syncthreads();

  // ---- ph layer 1: Hb -> A ----
  load_bias(ph_b1, j0, acc);
  gemv_pipe(Hb + e * RS, 0, ph_w1, j0, acc);
  silu_store_pad(A + e * RS, j0, acc);
  __syncthreads();

  // ---- ph layer 2 (no act) + residual ----
  load_bias(ph_b2, j0, acc);
  gemv_pipe(A + e * RS, 0, ph_w2, j0, acc);
  if (valid) {
    float* of = out + 60000 + (size_t)n * 128 + j0;
#pragma unroll
    for (int i = 0; i < 16; ++i) of[i] = acc[i] + Cb[e * RS + j0 + i];
  }

  // ---- vectors_out ----
  if (tid < NT * 3) {
    int nl = tid / 3, c = tid - nl * 3;
    int nn = n0 + nl;
    if (nn < N_NODES) {
      out[nn * 3 + c] = pos[nn * 3 + c] + shifts_acc[(size_t)nn * 3 + c] * INV_AVG;
    }
  }
}

// ---------------- launch ----------------
extern "C" void kernel_launch(void* const* d_in, const int* in_sizes, int n_in,
                              void* d_out, int out_size, void* d_ws, size_t ws_size,
                              hipStream_t stream) {
  const float* pos  = (const float*)d_in[0];
  const float* feat = (const float*)d_in[1];
  const float* pe_w0 = (const float*)d_in[2];
  const float* pe_b0 = (const float*)d_in[3];
  const float* pe_w1 = (const float*)d_in[4];
  const float* pe_b1 = (const float*)d_in[5];
  const float* px_w0 = (const float*)d_in[6];
  const float* px_b0 = (const float*)d_in[7];
  const float* px_w1 = (const float*)d_in[8];
  const float* px_b1 = (const float*)d_in[9];
  const float* px_out_w = (const float*)d_in[10];
  const float* px_out_b = (const float*)d_in[11];
  const float* e_w = (const float*)d_in[12];
  const float* e_b = (const float*)d_in[13];
  const float* ph_w0 = (const float*)d_in[14];
  const float* ph_b0 = (const float*)d_in[15];
  const float* ph_w1 = (const float*)d_in[16];
  const float* ph_b1 = (const float*)d_in[17];
  const float* ph_w2 = (const float*)d_in[18];
  const float* ph_b2 = (const float*)d_in[19];
  const int* snd = (const int*)d_in[20];
  const int* rcv = (const int*)d_in[21];
  float* ws = (float*)d_ws;
  float* out = (float*)d_out;

  hipMemsetAsync(d_ws, 0, (size_t)WS_FLOATS * sizeof(float), stream);

  edge_kernel<<<N_EDGES / ET, 256, 0, stream>>>(
      pos, feat, snd, rcv,
      pe_w0, pe_b0, pe_w1, pe_b1,
      px_w0, px_b0, px_w1, px_b1,
      px_out_w, px_out_b, e_w, e_b,
      ws + OFF_MACC, ws + OFF_SHIFT);

  node_kernel<<<(N_NODES + NT - 1) / NT, 256, 0, stream>>>(
      pos, feat, ph_w0, ph_b0, ph_w1, ph_b1, ph_w2, ph_b2,
      ws + OFF_MACC, ws + OFF_SHIFT, out);
}

// Round 4
// 531.029 us; speedup vs baseline: 22.5004x; 22.3776x over previous
//
#include <hip/hip_runtime.h>

#define N_NODES 20000
#define N_EDGES 640000
#define XS 136   // LDS activation row stride in bf16 units (128 + 8 pad -> 2-way banks only)

#define INV_SQRT_AVG 0.0070714082f   // 1/sqrt(19999)
#define INV_AVG      5.000250e-5f    // 1/19999

typedef __attribute__((ext_vector_type(8))) short bf16x8;
typedef __attribute__((ext_vector_type(4))) float f32x4;

__device__ __forceinline__ ushort f2b(float f) {
  unsigned x = __float_as_uint(f);
  unsigned r = (x + 0x7fffu + ((x >> 16) & 1u)) >> 16;   // RNE
  return (ushort)r;
}
__device__ __forceinline__ float silu(float v) { return v / (1.0f + __expf(-v)); }

// ---------------- weight prep: f32 [k][n] -> bf16 [n][k] (B-fragment friendly) ----
struct PrepArgs { const float* src[9]; };

__global__ __launch_bounds__(256) void prep_kernel(PrepArgs a, ushort* __restrict__ w) {
  int m = blockIdx.y;
  int i = blockIdx.x * 256 + threadIdx.x;   // 0..16383
  int k = i >> 7, n = i & 127;
  w[m * 16384 + n * 128 + k] = f2b(a.src[m][k * 128 + n]);
}

// ---------------- MFMA 64x32x128 per wave: acc[mt][ct] += X(64x128) * W(128x32) ----
// X: LDS bf16 rows stride XS. Wn0: global bf16 [n][k], pre-offset to this wave's n0.
__device__ __forceinline__ void gemm2(const ushort* X, const ushort* __restrict__ Wn0,
                                      int c, int q, f32x4 acc[4][2]) {
  const int kq = q * 8;
  bf16x8 b[2][4];
#pragma unroll
  for (int ct = 0; ct < 2; ++ct)
#pragma unroll
    for (int ks = 0; ks < 4; ++ks)
      b[ct][ks] = *(const bf16x8*)(Wn0 + (ct * 16 + c) * 128 + ks * 32 + kq);
#pragma unroll
  for (int mt = 0; mt < 4; ++mt)
#pragma unroll
    for (int ks = 0; ks < 4; ++ks) {
      bf16x8 a = *(const bf16x8*)(X + (mt * 16 + c) * XS + ks * 32 + kq);
      acc[mt][0] = __builtin_amdgcn_mfma_f32_16x16x32_bf16(a, b[0][ks], acc[mt][0], 0, 0, 0);
      acc[mt][1] = __builtin_amdgcn_mfma_f32_16x16x32_bf16(a, b[1][ks], acc[mt][1], 0, 0, 0);
    }
}

// stage one 128-f32 row (scaled) as bf16 into LDS row; 4 threads/row (sub=0..3)
__device__ __forceinline__ void stage_cvt(ushort* X, const float* __restrict__ src,
                                          int row, int sub, float scale) {
  const float4* s4 = (const float4*)src + sub * 8;
  uint* d = (uint*)(X + row * XS + sub * 32);
#pragma unroll
  for (int i = 0; i < 8; ++i) {
    float4 v = s4[i];
    d[2 * i]     = (unsigned)f2b(v.x * scale) | ((unsigned)f2b(v.y * scale) << 16);
    d[2 * i + 1] = (unsigned)f2b(v.z * scale) | ((unsigned)f2b(v.w * scale) << 16);
  }
}

// ---------------- edge kernel ----------------
__global__ __launch_bounds__(256, 3) void edge_kernel(
    const float* __restrict__ pos, const float* __restrict__ feat,
    const int* __restrict__ snd, const int* __restrict__ rcv,
    const ushort* __restrict__ wq,
    const float* __restrict__ pe_w0, const float* __restrict__ pe_b0,
    const float* __restrict__ pe_b1,
    const float* __restrict__ px_b0, const float* __restrict__ px_b1,
    const float* __restrict__ px_out_w, const float* __restrict__ px_out_b,
    const float* __restrict__ e_w, const float* __restrict__ e_b,
    float* __restrict__ outv, float* __restrict__ outf) {
  __shared__ ushort XA[64 * XS];
  __shared__ ushort XB[64 * XS];
  __shared__ float lenf[64], gp[64], pp[64], egl[64];
  __shared__ float vec3[64][3];
  __shared__ int erc[64];

  const int tid = threadIdx.x;
  const int e0 = blockIdx.x * 64;
  const int lane = tid & 63;
  const int wv = tid >> 6;
  const int c = lane & 15, q = lane >> 4;
  const int n0 = wv * 32;
  const int col0 = n0 + c, col1 = col0 + 16;

  if (tid < 64) {
    int s = snd[e0 + tid], r = rcv[e0 + tid];
    erc[tid] = r;
    float vx = pos[r * 3 + 0] - pos[s * 3 + 0];
    float vy = pos[r * 3 + 1] - pos[s * 3 + 1];
    float vz = pos[r * 3 + 2] - pos[s * 3 + 2];
    float n2 = vx * vx + vy * vy + vz * vz;
    float L = (n2 > 0.0f) ? sqrtf(n2) : 0.0f;
    vec3[tid][0] = vx; vec3[tid][1] = vy; vec3[tid][2] = vz;
    lenf[tid] = L; gp[tid] = 0.0f; pp[tid] = 0.0f;
  }
  {
    int row = tid >> 2, sub = tid & 3;
    stage_cvt(XA, feat + (size_t)snd[e0 + row] * 128, row, sub, 1.0f);
    stage_cvt(XB, feat + (size_t)rcv[e0 + row] * 128, row, sub, 1.0f);
  }
  __syncthreads();

  const f32x4 z4 = {0.f, 0.f, 0.f, 0.f};
  f32x4 acc[4][2];
#pragma unroll
  for (int mt = 0; mt < 4; ++mt) { acc[mt][0] = z4; acc[mt][1] = z4; }

  // ---- phi_e layer 0: sender half + receiver half ----
  gemm2(XA, wq + 0 * 16384 + n0 * 128, c, q, acc);
  gemm2(XB, wq + 1 * 16384 + n0 * 128, c, q, acc);
  __syncthreads();   // all waves done reading XA/XB

  {  // epilogue: + L*w256 + b, silu -> XA
    float b0 = pe_b0[col0], b1 = pe_b0[col1];
    float w0 = pe_w0[256 * 128 + col0], w1 = pe_w0[256 * 128 + col1];
#pragma unroll
    for (int mt = 0; mt < 4; ++mt)
#pragma unroll
      for (int rg = 0; rg < 4; ++rg) {
        int row = mt * 16 + q * 4 + rg;
        float L = lenf[row];
        XA[row * XS + col0] = f2b(silu(acc[mt][0][rg] + L * w0 + b0));
        XA[row * XS + col1] = f2b(silu(acc[mt][1][rg] + L * w1 + b1));
      }
  }
  __syncthreads();

  // ---- phi_e layer 1: XA -> m_ij (acc) ----
#pragma unroll
  for (int mt = 0; mt < 4; ++mt) { acc[mt][0] = z4; acc[mt][1] = z4; }
  gemm2(XA, wq + 2 * 16384 + n0 * 128, c, q, acc);
  {  // gate partials
    float b0 = pe_b1[col0], b1 = pe_b1[col1];
    float ew0 = e_w[col0], ew1 = e_w[col1];
#pragma unroll
    for (int mt = 0; mt < 4; ++mt)
#pragma unroll
      for (int rg = 0; rg < 4; ++rg) {
        float m0 = silu(acc[mt][0][rg] + b0);
        float m1 = silu(acc[mt][1][rg] + b1);
        float rp = m0 * ew0 + m1 * ew1;
        rp += __shfl_xor(rp, 1); rp += __shfl_xor(rp, 2);
        rp += __shfl_xor(rp, 4); rp += __shfl_xor(rp, 8);
        if (c == 0) atomicAdd(&gp[mt * 16 + q * 4 + rg], rp);
      }
  }
  __syncthreads();
  if (tid < 64) egl[tid] = 1.0f / (1.0f + __expf(-(gp[tid] + e_b[0])));
  __syncthreads();
  {  // m -> XB (ungated, for phi_x) + gated global atomics into outf (m_i accumulator)
    float b0 = pe_b1[col0], b1 = pe_b1[col1];
#pragma unroll
    for (int mt = 0; mt < 4; ++mt)
#pragma unroll
      for (int rg = 0; rg < 4; ++rg) {
        int row = mt * 16 + q * 4 + rg;
        float m0 = silu(acc[mt][0][rg] + b0);
        float m1 = silu(acc[mt][1][rg] + b1);
        XB[row * XS + col0] = f2b(m0);
        XB[row * XS + col1] = f2b(m1);
        float eg = egl[row];
        size_t rb = (size_t)erc[row] * 128;
        atomicAdd(&outf[rb + col0], m0 * eg);
        atomicAdd(&outf[rb + col1], m1 * eg);
      }
  }
  __syncthreads();

  // ---- phi_x layer 0: XB -> XA ----
#pragma unroll
  for (int mt = 0; mt < 4; ++mt) { acc[mt][0] = z4; acc[mt][1] = z4; }
  gemm2(XB, wq + 3 * 16384 + n0 * 128, c, q, acc);
  {
    float b0 = px_b0[col0], b1 = px_b0[col1];
#pragma unroll
    for (int mt = 0; mt < 4; ++mt)
#pragma unroll
      for (int rg = 0; rg < 4; ++rg) {
        int row = mt * 16 + q * 4 + rg;
        XA[row * XS + col0] = f2b(silu(acc[mt][0][rg] + b0));
        XA[row * XS + col1] = f2b(silu(acc[mt][1][rg] + b1));
      }
  }
  __syncthreads();

  // ---- phi_x layer 1: XA -> Dense(1) tail ----
#pragma unroll
  for (int mt = 0; mt < 4; ++mt) { acc[mt][0] = z4; acc[mt][1] = z4; }
  gemm2(XA, wq + 4 * 16384 + n0 * 128, c, q, acc);
  {
    float b0 = px_b1[col0], b1 = px_b1[col1];
    float pw0 = px_out_w[col0], pw1 = px_out_w[col1];
#pragma unroll
    for (int mt = 0; mt < 4; ++mt)
#pragma unroll
      for (int rg = 0; rg < 4; ++rg) {
        float rp = silu(acc[mt][0][rg] + b0) * pw0 + silu(acc[mt][1][rg] + b1) * pw1;
        rp += __shfl_xor(rp, 1); rp += __shfl_xor(rp, 2);
        rp += __shfl_xor(rp, 4); rp += __shfl_xor(rp, 8);
        if (c == 0) atomicAdd(&pp[mt * 16 + q * 4 + rg], rp);
      }
  }
  __syncthreads();
  if (tid < 192) {
    int ee = tid / 3, cc = tid - ee * 3;
    float phi = pp[ee] + px_out_b[0];
    float sh = phi * vec3[ee][cc] / (1.0f + lenf[ee]);
    atomicAdd(&outv[(size_t)erc[ee] * 3 + cc], sh);
  }
}

// ---------------- node kernel ----------------
__global__ __launch_bounds__(256, 3) void node_kernel(
    const float* __restrict__ pos, const float* __restrict__ feat,
    const ushort* __restrict__ wq,
    const float* __restrict__ ph_b0, const float* __restrict__ ph_b1,
    const float* __restrict__ ph_b2,
    float* __restrict__ outv, float* __restrict__ outf) {
  __shared__ ushort XA[64 * XS];
  __shared__ ushort XB[64 * XS];

  const int tid = threadIdx.x;
  const int nb0 = blockIdx.x * 64;
  const int lane = tid & 63;
  const int wv = tid >> 6;
  const int c = lane & 15, q = lane >> 4;
  const int n0 = wv * 32;
  const int col0 = n0 + c, col1 = col0 + 16;

  {
    int row = tid >> 2, sub = tid & 3;
    int nn = nb0 + row; if (nn >= N_NODES) nn = N_NODES - 1;
    stage_cvt(XA, outf + (size_t)nn * 128, row, sub, INV_SQRT_AVG);  // m_i
    stage_cvt(XB, feat + (size_t)nn * 128, row, sub, 1.0f);
  }
  __syncthreads();

  const f32x4 z4 = {0.f, 0.f, 0.f, 0.f};
  f32x4 acc[4][2];
#pragma unroll
  for (int mt = 0; mt < 4; ++mt) { acc[mt][0] = z4; acc[mt][1] = z4; }

  // ---- ph layer 0: [m_i | feat] ----
  gemm2(XA, wq + 5 * 16384 + n0 * 128, c, q, acc);
  gemm2(XB, wq + 6 * 16384 + n0 * 128, c, q, acc);
  __syncthreads();
  {
    float b0 = ph_b0[col0], b1 = ph_b0[col1];
#pragma unroll
    for (int mt = 0; mt < 4; ++mt)
#pragma unroll
      for (int rg = 0; rg < 4; ++rg) {
        int row = mt * 16 + q * 4 + rg;
        XA[row * XS + col0] = f2b(silu(acc[mt][0][rg] + b0));
        XA[row * XS + col1] = f2b(silu(acc[mt][1][rg] + b1));
      }
  }
  __syncthreads();

  // ---- ph layer 1: XA -> XB ----
#pragma unroll
  for (int mt = 0; mt < 4; ++mt) { acc[mt][0] = z4; acc[mt][1] = z4; }
  gemm2(XA, wq + 7 * 16384 + n0 * 128, c, q, acc);
  {
    float b0 = ph_b1[col0], b1 = ph_b1[col1];
#pragma unroll
    for (int mt = 0; mt < 4; ++mt)
#pragma unroll
      for (int rg = 0; rg < 4; ++rg) {
        int row = mt * 16 + q * 4 + rg;
        XB[row * XS + col0] = f2b(silu(acc[mt][0][rg] + b0));
        XB[row * XS + col1] = f2b(silu(acc[mt][1][rg] + b1));
      }
  }
  __syncthreads();

  // ---- ph layer 2 (no act) + residual, write final features ----
#pragma unroll
  for (int mt = 0; mt < 4; ++mt) { acc[mt][0] = z4; acc[mt][1] = z4; }
  gemm2(XB, wq + 8 * 16384 + n0 * 128, c, q, acc);
  {
    float b0 = ph_b2[col0], b1 = ph_b2[col1];
#pragma unroll
    for (int mt = 0; mt < 4; ++mt)
#pragma unroll
      for (int rg = 0; rg < 4; ++rg) {
        int row = mt * 16 + q * 4 + rg;
        int nn = nb0 + row;
        if (nn < N_NODES) {
          size_t o = (size_t)nn * 128;
          outf[o + col0] = acc[mt][0][rg] + b0 + feat[o + col0];
          outf[o + col1] = acc[mt][1][rg] + b1 + feat[o + col1];
        }
      }
  }
  // ---- vectors_out: read accumulated shifts in-place, finalize ----
  if (tid < 192) {
    int nl = tid / 3, cc = tid - nl * 3;
    int nn = nb0 + nl;
    if (nn < N_NODES)
      outv[nn * 3 + cc] = pos[nn * 3 + cc] + outv[nn * 3 + cc] * INV_AVG;
  }
}

// ---------------- launch ----------------
extern "C" void kernel_launch(void* const* d_in, const int* in_sizes, int n_in,
                              void* d_out, int out_size, void* d_ws, size_t ws_size,
                              hipStream_t stream) {
  const float* pos  = (const float*)d_in[0];
  const float* feat = (const float*)d_in[1];
  const float* pe_w0 = (const float*)d_in[2];
  const float* pe_b0 = (const float*)d_in[3];
  const float* pe_w1 = (const float*)d_in[4];
  const float* pe_b1 = (const float*)d_in[5];
  const float* px_w0 = (const float*)d_in[6];
  const float* px_b0 = (const float*)d_in[7];
  const float* px_w1 = (const float*)d_in[8];
  const float* px_b1 = (const float*)d_in[9];
  const float* px_out_w = (const float*)d_in[10];
  const float* px_out_b = (const float*)d_in[11];
  const float* e_w = (const float*)d_in[12];
  const float* e_b = (const float*)d_in[13];
  const float* ph_w0 = (const float*)d_in[14];
  const float* ph_b0 = (const float*)d_in[15];
  const float* ph_w1 = (const float*)d_in[16];
  const float* ph_b1 = (const float*)d_in[17];
  const float* ph_w2 = (const float*)d_in[18];
  const float* ph_b2 = (const float*)d_in[19];
  const int* snd = (const int*)d_in[20];
  const int* rcv = (const int*)d_in[21];
  ushort* wq = (ushort*)d_ws;
  float* out = (float*)d_out;

  // d_out doubles as the accumulator (m_i in features region, shifts in vectors region)
  hipMemsetAsync(d_out, 0, (size_t)out_size * sizeof(float), stream);

  PrepArgs a;
  a.src[0] = pe_w0;              // k 0..127   (sender)
  a.src[1] = pe_w0 + 128 * 128;  // k 128..255 (receiver)
  a.src[2] = pe_w1;
  a.src[3] = px_w0;
  a.src[4] = px_w1;
  a.src[5] = ph_w0;              // k 0..127   (m_i)
  a.src[6] = ph_w0 + 128 * 128;  // k 128..255 (feat)
  a.src[7] = ph_w1;
  a.src[8] = ph_w2;
  prep_kernel<<<dim3(64, 9), 256, 0, stream>>>(a, wq);

  edge_kernel<<<N_EDGES / 64, 256, 0, stream>>>(
      pos, feat, snd, rcv, wq,
      pe_w0, pe_b0, pe_b1, px_b0, px_b1,
      px_out_w, px_out_b, e_w, e_b,
      out, out + 60000);

  node_kernel<<<(N_NODES + 63) / 64, 256, 0, stream>>>(
      pos, feat, wq, ph_b0, ph_b1, ph_b2,
      out, out + 60000);
}